// Round 13
// baseline (294.279 us; speedup 1.0000x reference)
//
#include <hip/hip_runtime.h>
#include <hip/hip_bf16.h>

// ---------------------------------------------------------------------------
// GumbelNeRF fused kernel, round 18: pass-1 row-split (wave-shared weights).
//
// R13-R17 anomaly: dur invariant ~213us across 2blk/3blk, dbuf/single,
// 2x LDS traffic, 2x conflicts — no pipe >40% busy, every within-phase fix
// absorbed. The invariant in all configs: per-block 442KB weight stream from
// L2 with col-split waves (each wave loads DIFFERENT weights -> L1 useless).
// R18 inverts pass 1: each wave owns 16 POINTS (rows w*16+c), iterates all
// 8 col-tiles j per expert. All 4 waves issue IDENTICAL weight addresses in
// near-lockstep -> L1 serves 3/4, L2 weight traffic /4. Structural bonuses:
//  - per-wave Y slice = 16 rows -> Ahw[4]+Alw[4] (32 regs) fully hoisted,
//    ZERO pass-1 LDS reads (conflicts 12.3M -> ~4M predicted);
//  - sigma owned per-wave -> atomicAdd + sRed zero-init deleted;
//  - mapping: tbase=(e*8+j)*4 (j replaces 2w+i), wsv[j][r]=w_sig[j*16+q*4+r],
//    point = w*16+c; q-reduce via shfl_xor(16,32) as before.
// Everything outside pass 1 byte-identical to R17 (incl. coalesced prep).
// ---------------------------------------------------------------------------

#define NPTS 131072
#define PT 64
#define NTH 256
#define NBLK (NPTS / PT)
#define INV2048 (1.0f / 2048.0f)

// ws sections (f16 element offsets) — identical to rounds 2-17
#define WS_ENC_H 0
#define WS_ENC_L 8192
#define WS_SH_H  16384
#define WS_SH_L  147456
#define WS_R1_H  278528

// LDS byte offsets, total 40960
#define OFF_YH   0      // sYh [64][136] f16 = 17408 ; pass2b+: sH [64][68] f32
#define OFF_B    17408  // 21504 B: sPEh[64][72](9216)+sPEl(9216) | sYl[64][136] | sSB[64][168] f16
#define OFF_RED  38912  // sRed [8][64] f32 = 2048 (per-wave direct store now)
#define SMEM_SZ  40960

// smalls live in sSB row-pad (cols 160..167 = bytes 320..335 of each 336B row)
#define S_LIST(s) (*(int*)(smem + OFF_B + (s) * 336 + 320))
#define S_BID(p)  (*(int*)(smem + OFF_B + (p) * 336 + 324))
#define S_CNT(e)  (*(int*)(smem + OFF_B + (e) * 336 + 328))
#define S_OFF(e)  (*(int*)(smem + OFF_B + (e) * 336 + 332))

typedef __attribute__((ext_vector_type(8))) _Float16 f16x8;
typedef __attribute__((ext_vector_type(4))) _Float16 f16x4;
typedef __attribute__((ext_vector_type(4))) float f32x4;

#define MFMA(a, b, c) __builtin_amdgcn_mfma_f32_16x16x32_f16((a), (b), (c), 0, 0, 0)

__device__ __forceinline__ unsigned rotl32(unsigned x, int d) {
  return (x << d) | (x >> (32 - d));
}

// JAX threefry2x32, keys (0,42), counter (0, flat), partitionable fold.
__device__ __forceinline__ float gumbel_for(unsigned flat) {
  const unsigned k0 = 0u, k1 = 42u;
  const unsigned ks2 = k0 ^ k1 ^ 0x1BD11BDAu;
  unsigned x0 = 0u + k0;
  unsigned x1 = flat + k1;
#define TF_RND(r) { x0 += x1; x1 = rotl32(x1, r); x1 ^= x0; }
  TF_RND(13) TF_RND(15) TF_RND(26) TF_RND(6)
  x0 += k1;  x1 += ks2 + 1u;
  TF_RND(17) TF_RND(29) TF_RND(16) TF_RND(24)
  x0 += ks2; x1 += k0 + 2u;
  TF_RND(13) TF_RND(15) TF_RND(26) TF_RND(6)
  x0 += k0;  x1 += k1 + 3u;
  TF_RND(17) TF_RND(29) TF_RND(16) TF_RND(24)
  x0 += k1;  x1 += ks2 + 4u;
  TF_RND(13) TF_RND(15) TF_RND(26) TF_RND(6)
  x0 += ks2; x1 += k0 + 5u;
#undef TF_RND
  unsigned bits = x0 ^ x1;
  float u = __uint_as_float((bits >> 9) | 0x3f800000u) - 1.0f;
  return -logf(-logf(u + 1e-20f) + 1e-20f);
}

// ---------------------------------------------------------------------------
// prep: fp32 weights -> fragment-linear f16 (scaled split) in ws.
// Coalesced reads (R17): thread->(k,n), n fastest.
// ---------------------------------------------------------------------------
__global__ void prep_kernel(const float* __restrict__ W_enc,
                            const float* __restrict__ W_sh,
                            const float* __restrict__ W_r1,
                            _Float16* __restrict__ ws) {
  int tid = blockIdx.x * 256 + threadIdx.x;
  if (tid < 8192) {
    int tile = tid >> 9, r = tid & 511;
    int kk = r >> 4, cc = r & 15;
    int nt = tile >> 1, kt = tile & 1;
    int k = kt * 32 + kk, n = nt * 16 + cc;
    float v = (k < 63) ? W_enc[k * 128 + n] : 0.0f;
    int off = tile * 512 + (kk >> 3) * 128 + cc * 8 + (kk & 7);
    _Float16 h = (_Float16)v;
    ws[WS_ENC_H + off] = h;
    ws[WS_ENC_L + off] = (_Float16)((v - (float)h) * 2048.0f);
  } else if (tid < 139264) {
    int s = tid - 8192;
    int tile = s >> 9, r = s & 511;
    int kk = r >> 4, cc = r & 15;
    int e = tile >> 5, nt = (tile >> 2) & 7, kt = tile & 3;
    int k = kt * 32 + kk, n = nt * 16 + cc;
    float v = W_sh[e * 16384 + k * 128 + n];
    int off = tile * 512 + (kk >> 3) * 128 + cc * 8 + (kk & 7);
    _Float16 h = (_Float16)v;
    ws[WS_SH_H + off] = h;
    ws[WS_SH_L + off] = (_Float16)((v - (float)h) * 2048.0f);
  } else if (tid < 221184) {
    int s = tid - 139264;
    int tile = s >> 9, r = s & 511;
    int kk = r >> 4, cc = r & 15;
    int e = tile / 20, rr = tile % 20;
    int nt = rr / 5, kt = rr % 5;
    int k = kt * 32 + kk, n = nt * 16 + cc;
    float v = (k < 155) ? W_r1[e * 9920 + k * 64 + n] : 0.0f;
    int off = tile * 512 + (kk >> 3) * 128 + cc * 8 + (kk & 7);
    ws[WS_R1_H + off] = (_Float16)v;
  }
}

// ---------------------------------------------------------------------------
__global__ __launch_bounds__(NTH, 3)
void nerf_moe_kernel(const float* __restrict__ x,
                     const float* __restrict__ b_enc,
                     const float* __restrict__ b_sh,
                     const float* __restrict__ w_sig, const float* __restrict__ b_sig,
                     const float* __restrict__ b_r1,
                     const float* __restrict__ W_r2,  const float* __restrict__ b_r2,
                     const _Float16* __restrict__ wsw,
                     float* __restrict__ out) {
  __shared__ __align__(16) unsigned char smem[SMEM_SZ];
  _Float16* sYh  = (_Float16*)(smem + OFF_YH);
  float*    sH   = (float*)(smem + OFF_YH);
  _Float16* sYl  = (_Float16*)(smem + OFF_B);
  _Float16* sPEh = (_Float16*)(smem + OFF_B);
  _Float16* sPEl = (_Float16*)(smem + OFF_B + 9216);
  _Float16* sSB  = (_Float16*)(smem + OFF_B);
  float*    sRed = (float*)(smem + OFF_RED);    // [8][64], per-wave owned

  const int t  = threadIdx.x;
  const int w  = t >> 6;        // wave id 0..3
  const int L  = t & 63;        // lane
  const int q  = L >> 4;        // quad 0..3
  const int c  = L & 15;
  const int n0 = blockIdx.x * PT;

  // ---- phase 0: xyz positional encoding ----
  for (int idx = t; idx < PT * 64; idx += NTH) {
    int p = idx >> 6, f = idx & 63;
    const float* xr = x + (size_t)(n0 + p) * 6;
    float v;
    if (f < 3)       v = xr[f];
    else if (f < 33) { int g = f - 3;  v = sinf(xr[g % 3] * (float)(1 << (g / 3))); }
    else if (f < 63) { int g = f - 33; v = cosf(xr[g % 3] * (float)(1 << (g / 3))); }
    else             v = 0.0f;
    _Float16 h = (_Float16)v;
    sPEh[p * 72 + f] = h;
    sPEl[p * 72 + f] = (_Float16)((v - (float)h) * 2048.0f);
  }
  __syncthreads();                                   // (1)

  // ---- phase A: Y = relu(PE @ W_enc + b) via MFMA, mt split in halves ----
  {
    f16x8 beh[2][2], bel[2][2];
    #pragma unroll
    for (int ntL = 0; ntL < 2; ++ntL)
      #pragma unroll
      for (int kt = 0; kt < 2; ++kt) {
        int tile = (2 * w + ntL) * 2 + kt;
        beh[ntL][kt] = *(const f16x8*)(wsw + WS_ENC_H + tile * 512 + L * 8);
        bel[ntL][kt] = *(const f16x8*)(wsw + WS_ENC_L + tile * 512 + L * 8);
      }
    f32x4 a1[4][2], a2[4][2];
    #pragma unroll
    for (int mt = 0; mt < 4; ++mt)
      #pragma unroll
      for (int ntL = 0; ntL < 2; ++ntL) { a1[mt][ntL] = (f32x4)0.0f; a2[mt][ntL] = (f32x4)0.0f; }
    // two halves over mt; pah/pal registers reused between halves
    #pragma unroll
    for (int half = 0; half < 2; ++half) {
      f16x8 pah[2][2], pal[2][2];
      #pragma unroll
      for (int m = 0; m < 2; ++m)
        #pragma unroll
        for (int kt = 0; kt < 2; ++kt) {
          int off = ((half * 2 + m) * 16 + c) * 72 + kt * 32 + q * 8;
          pah[m][kt] = *(const f16x8*)(sPEh + off);
          pal[m][kt] = *(const f16x8*)(sPEl + off);
        }
      __builtin_amdgcn_s_setprio(1);
      #pragma unroll
      for (int kt = 0; kt < 2; ++kt)
        #pragma unroll
        for (int m = 0; m < 2; ++m)
          #pragma unroll
          for (int ntL = 0; ntL < 2; ++ntL) {
            int mt = half * 2 + m;
            a1[mt][ntL] = MFMA(pah[m][kt], beh[ntL][kt], a1[mt][ntL]);
            a2[mt][ntL] = MFMA(pah[m][kt], bel[ntL][kt], a2[mt][ntL]);
            a2[mt][ntL] = MFMA(pal[m][kt], beh[ntL][kt], a2[mt][ntL]);
          }
      __builtin_amdgcn_s_setprio(0);
      asm volatile("" ::: "memory");   // fence: keep halves' LDS loads apart
    }
    __syncthreads();                                 // (2) sPE reads done -> sYl writable
    float bb0 = b_enc[(2 * w) * 16 + c];
    float bb1 = b_enc[(2 * w + 1) * 16 + c];
    #pragma unroll
    for (int mt = 0; mt < 4; ++mt)
      #pragma unroll
      for (int ntL = 0; ntL < 2; ++ntL) {
        float bb = ntL ? bb1 : bb0;
        int col = (2 * w + ntL) * 16 + c;
        #pragma unroll
        for (int r = 0; r < 4; ++r) {
          float v = fmaxf(a1[mt][ntL][r] + a2[mt][ntL][r] * INV2048 + bb, 0.0f);
          int row = mt * 16 + q * 4 + r;
          _Float16 h = (_Float16)v;
          sYh[row * 136 + col] = h;
          sYl[row * 136 + col] = (_Float16)((v - (float)h) * 2048.0f);
        }
      }
  }
  __syncthreads();                                   // (3)

  // ---- pass 1 setup: hoist THIS WAVE's 16 Y rows (hi+lo, 32 regs) and
  // the full w_sig (8 col-tiles x f32x4). Zero pass-1 LDS reads after this.
  f16x8 Ahw[4], Alw[4];
  #pragma unroll
  for (int kt = 0; kt < 4; ++kt) {
    Ahw[kt] = *(const f16x8*)(sYh + (w * 16 + c) * 136 + kt * 32 + q * 8);
    Alw[kt] = *(const f16x8*)(sYl + (w * 16 + c) * 136 + kt * 32 + q * 8);
  }
  f32x4 wsv[8];
  #pragma unroll
  for (int j = 0; j < 8; ++j)
    wsv[j] = *(const f32x4*)(w_sig + j * 16 + q * 4);

  // ---- pass 1: row-split. Each wave: points w*16+c, all 8 col-tiles per
  // expert. All waves issue IDENTICAL weight addresses -> L1 shared.
  #pragma unroll 1
  for (int e = 0; e < 8; ++e) {
    float psum = 0.f;
    #pragma unroll
    for (int j = 0; j < 8; ++j) {
      int tbase = (e * 8 + j) * 4;
      f16x8 bh[4], bl[4];
      #pragma unroll
      for (int kt = 0; kt < 4; ++kt) {
        bh[kt] = *(const f16x8*)(wsw + WS_SH_H + (tbase + kt) * 512 + L * 8);
        bl[kt] = *(const f16x8*)(wsw + WS_SH_L + (tbase + kt) * 512 + L * 8);
      }
      f32x4 bb = *(const f32x4*)(b_sh + e * 128 + j * 16 + q * 4);
      f32x4 a1 = (f32x4)0.0f, a2 = (f32x4)0.0f;
      __builtin_amdgcn_s_setprio(1);
      #pragma unroll
      for (int kt = 0; kt < 4; ++kt) {
        a1 = MFMA(bh[kt], Ahw[kt], a1);
        a2 = MFMA(bl[kt], Ahw[kt], a2);
        a2 = MFMA(bh[kt], Alw[kt], a2);
      }
      __builtin_amdgcn_s_setprio(0);
      #pragma unroll
      for (int r = 0; r < 4; ++r) {
        float sv = fmaxf(fmaf(a2[r], INV2048, a1[r]) + bb[r], 0.0f);
        psum = fmaf(sv, wsv[j][r], psum);
      }
    }
    // q-reduction only (cols split across q quads); points owned per-wave.
    psum += __shfl_xor(psum, 16);
    psum += __shfl_xor(psum, 32);
    if (q == 0) sRed[e * 64 + w * 16 + c] = psum;
  }
  __syncthreads();                                   // (4) — only pass-1 barrier

  // ---- argmax: distributed, 4 threads/point x 2 experts, gumbel inline ----
  {
    int pt = t >> 2;
    int eb = (t & 3) * 2;
    float best = -1e30f, bsig = 0.0f;
    int bide = 0;
    const float bs = b_sig[0];
    #pragma unroll
    for (int j = 0; j < 2; ++j) {
      int e = eb + j;
      float s = sRed[e * 64 + pt];
      float dotv = s + bs;
      float sig = fmaxf(dotv, 0.0f) + log1pf(expf(-fabsf(dotv)));
      float z = logf(sig + 1e-10f) / 0.166667f;
      float score = z + gumbel_for((unsigned)((n0 + pt) * 8 + e));
      if (score > best) { best = score; bsig = sig; bide = e; }
    }
    #pragma unroll
    for (int m = 1; m <= 2; m <<= 1) {
      float oS  = __shfl_xor(best, m);
      float oSg = __shfl_xor(bsig, m);
      int   oI  = __shfl_xor(bide, m);
      if (oS > best || (oS == best && oI < bide)) { best = oS; bsig = oSg; bide = oI; }
    }
    if ((t & 3) == 0) {
      S_BID(pt) = bide;                // row-pad slot; sYl dead, sSB not yet
      out[(size_t)(n0 + pt) * 4 + 3] = bsig;
    }
  }
  __syncthreads();                                   // (5)

  // ---- bucket lists: wave-0 ballot build ----
  if (t < 64) {
    int bid = S_BID(t);
    unsigned long long below = t ? ((~0ULL) >> (64 - t)) : 0ULL;
    int off = 0;
    #pragma unroll
    for (int e = 0; e < 8; ++e) {
      unsigned long long m = __ballot(bid == e);
      int cnt = __popcll(m);
      if (t == e) { S_CNT(e) = cnt; S_OFF(e) = off; }
      if (bid == e) {
        int rank = __popcll(m & below);
        S_LIST(off + rank) = t;
      }
      off += cnt;
    }
  }
  __syncthreads();                                   // (6)

  // ---- pass 2a: viewdir PE into sSB + winner S recompute (transposed) ----
  for (int idx = t; idx < PT * 32; idx += NTH) {
    int s = idx >> 5, cc = idx & 31;
    int pt = S_LIST(s);
    const float* xr = x + (size_t)(n0 + pt) * 6 + 3;
    float v;
    if (cc < 3)       v = xr[cc];
    else if (cc < 15) { int g = cc - 3;  v = sinf(xr[g % 3] * (float)(1 << (g / 3))); }
    else if (cc < 27) { int g = cc - 15; v = cosf(xr[g % 3] * (float)(1 << (g / 3))); }
    else              v = 0.0f;
    sSB[s * 168 + 128 + cc] = (_Float16)v;
  }
  #pragma unroll 1
  for (int ei = 0; ei < 2; ++ei) {
    int e = 2 * w + ei;
    int cnt = S_CNT(e), off = S_OFF(e);
    for (int base = 0; base < cnt; base += 16) {
      int sidx = base + c; if (sidx >= cnt) sidx = cnt - 1;
      int pt = S_LIST(off + sidx);
      f16x8 yb[4];
      #pragma unroll
      for (int kt = 0; kt < 4; ++kt)
        yb[kt] = *(const f16x8*)(sYh + pt * 136 + kt * 32 + q * 8);
      f32x4 acc[8];
      #pragma unroll
      for (int jt = 0; jt < 8; ++jt) acc[jt] = (f32x4)0.0f;
      // jt split into 2 halves of 4: <=16 weight frags in flight (64 VGPR)
      #pragma unroll
      for (int jh = 0; jh < 2; ++jh) {
        __builtin_amdgcn_s_setprio(1);
        #pragma unroll
        for (int jt2 = 0; jt2 < 4; ++jt2) {
          int jt = jh * 4 + jt2;
          #pragma unroll
          for (int kt = 0; kt < 4; ++kt) {
            f16x8 a = *(const f16x8*)(wsw + WS_SH_H + ((e * 8 + jt) * 4 + kt) * 512 + L * 8);
            acc[jt] = MFMA(a, yb[kt], acc[jt]);
          }
        }
        __builtin_amdgcn_s_setprio(0);
        asm volatile("" ::: "memory"); // fence: limit weight-load hoisting
      }
      bool wr = (base + c) < cnt;
      int slot = off + base + c;
      #pragma unroll
      for (int jt = 0; jt < 8; ++jt) {
        f32x4 bb = *(const f32x4*)(b_sh + e * 128 + jt * 16 + q * 4);
        f16x4 v;
        #pragma unroll
        for (int r = 0; r < 4; ++r)
          v[r] = (_Float16)fmaxf(acc[jt][r] + bb[r], 0.0f);
        if (wr) *(f16x4*)(sSB + slot * 168 + jt * 16 + q * 4) = v;
      }
    }
  }
  __syncthreads();                                   // (7) sYh dead -> sH writable

  // ---- pass 2b: rgb layer 1 via MFMA ([S;vd] @ W_r1) ----
  #pragma unroll 1
  for (int ei = 0; ei < 2; ++ei) {
    int e = 2 * w + ei;
    int cnt = S_CNT(e), off = S_OFF(e);
    for (int base = 0; base < cnt; base += 16) {
      int sidx = base + c; if (sidx >= cnt) sidx = cnt - 1;
      int slot = off + sidx;
      f16x8 ag[5];
      #pragma unroll
      for (int kt = 0; kt < 5; ++kt)
        ag[kt] = *(const f16x8*)(sSB + slot * 168 + kt * 32 + q * 8);
      f32x4 hacc[4];
      #pragma unroll
      for (int nt = 0; nt < 4; ++nt) hacc[nt] = (f32x4)0.0f;
      // nt split into 2 halves of 2: <=10 weight frags in flight (40 VGPR)
      #pragma unroll
      for (int nh = 0; nh < 2; ++nh) {
        __builtin_amdgcn_s_setprio(1);
        #pragma unroll
        for (int nt2 = 0; nt2 < 2; ++nt2) {
          int nt = nh * 2 + nt2;
          #pragma unroll
          for (int kt = 0; kt < 5; ++kt) {
            f16x8 bf = *(const f16x8*)(wsw + WS_R1_H + ((e * 4 + nt) * 5 + kt) * 512 + L * 8);
            hacc[nt] = MFMA(ag[kt], bf, hacc[nt]);
          }
        }
        __builtin_amdgcn_s_setprio(0);
        asm volatile("" ::: "memory"); // fence: limit weight-load hoisting
      }
      #pragma unroll
      for (int nt = 0; nt < 4; ++nt) {
        float bb = b_r1[e * 64 + nt * 16 + c];
        #pragma unroll
        for (int r = 0; r < 4; ++r) {
          int m = q * 4 + r;
          if (base + m < cnt)
            sH[(off + base + m) * 68 + nt * 16 + c] = fmaxf(hacc[nt][r] + bb, 0.0f);
        }
      }
    }
  }
  __syncthreads();                                   // (8)

  // ---- layer 2: rgb = sigmoid(h @ W_r2 + b) ----
  if (t < 192) {
    int s = t / 3, o = t - s * 3;
    int pt = S_LIST(s);
    int e = S_BID(pt);
    float a = b_r2[e * 3 + o];
    const float* w2 = W_r2 + e * 192 + o;
    #pragma unroll
    for (int jj = 0; jj < 64; jj += 4) {
      f32x4 h4 = *(const f32x4*)(sH + s * 68 + jj);
      a = fmaf(h4.x, w2[jj * 3], a);
      a = fmaf(h4.y, w2[jj * 3 + 3], a);
      a = fmaf(h4.z, w2[jj * 3 + 6], a);
      a = fmaf(h4.w, w2[jj * 3 + 9], a);
    }
    out[(size_t)(n0 + pt) * 4 + o] = 1.0f / (1.0f + expf(-a));
  }
}

extern "C" void kernel_launch(void* const* d_in, const int* in_sizes, int n_in,
                              void* d_out, int out_size, void* d_ws, size_t ws_size,
                              hipStream_t stream) {
  (void)in_sizes; (void)n_in; (void)ws_size; (void)out_size;
  const float* x     = (const float*)d_in[0];
  const float* W_enc = (const float*)d_in[1];
  const float* b_enc = (const float*)d_in[2];
  const float* W_sh  = (const float*)d_in[3];
  const float* b_sh  = (const float*)d_in[4];
  const float* w_sig = (const float*)d_in[5];
  const float* b_sig = (const float*)d_in[6];
  const float* W_r1  = (const float*)d_in[7];
  const float* b_r1  = (const float*)d_in[8];
  const float* W_r2  = (const float*)d_in[9];
  const float* b_r2  = (const float*)d_in[10];
  _Float16* ws = (_Float16*)d_ws;     // needs 720896 B
  float* outp = (float*)d_out;
  prep_kernel<<<864, 256, 0, stream>>>(W_enc, W_sh, W_r1, ws);
  nerf_moe_kernel<<<NBLK, NTH, 0, stream>>>(x, b_enc, b_sh, w_sig, b_sig,
                                            b_r1, W_r2, b_r2, ws, outp);
}

// Round 14
// 258.228 us; speedup vs baseline: 1.1396x; 1.1396x over previous
//
#include <hip/hip_runtime.h>
#include <hip/hip_bf16.h>

// ---------------------------------------------------------------------------
// GumbelNeRF fused kernel, round 19: revert R18; R17 champion kernel +
// prep v3 (float4 reads, 4 elem/thread, 216 blocks).
//
// R18 post-mortem: row-split REGRESSED 213->254 despite conflicts 12.3M->1.7M.
// Mechanism: col-split = 128 weight-load insts/wave in pass 1; row-split =
// 512/wave (every wave walks the full stream). Weight path is load-ISSUE/
// latency-bound, not L2-BW-bound -> sharing bytes across waves doesn't pay
// for 4x instruction count. This also explains the R13-R17 invariance.
// nerf_moe_kernel reverted to R17 exactly (213us dispatch, occ 29%).
// prep v3: thread handles 4 consecutive cc -> float4 coalesced reads,
// 55296 threads = 216 blocks (was 864). Targets the 43us bench-dispatch gap.
// ---------------------------------------------------------------------------

#define NPTS 131072
#define PT 64
#define NTH 256
#define NBLK (NPTS / PT)
#define INV2048 (1.0f / 2048.0f)

// ws sections (f16 element offsets) — identical to rounds 2-18
#define WS_ENC_H 0
#define WS_ENC_L 8192
#define WS_SH_H  16384
#define WS_SH_L  147456
#define WS_R1_H  278528

// LDS byte offsets, total 40960
#define OFF_YH   0      // sYh [64][136] f16 = 17408 ; pass2b+: sH [64][68] f32
#define OFF_B    17408  // 21504 B: sPEh[64][72](9216)+sPEl(9216) | sYl[64][136] | sSB[64][168] f16
#define OFF_RED  38912  // sRed [8][64] f32 = 2048 (atomic cross-wave sum)
#define SMEM_SZ  40960

// smalls live in sSB row-pad (cols 160..167 = bytes 320..335 of each 336B row)
#define S_LIST(s) (*(int*)(smem + OFF_B + (s) * 336 + 320))
#define S_BID(p)  (*(int*)(smem + OFF_B + (p) * 336 + 324))
#define S_CNT(e)  (*(int*)(smem + OFF_B + (e) * 336 + 328))
#define S_OFF(e)  (*(int*)(smem + OFF_B + (e) * 336 + 332))

typedef __attribute__((ext_vector_type(8))) _Float16 f16x8;
typedef __attribute__((ext_vector_type(4))) _Float16 f16x4;
typedef __attribute__((ext_vector_type(4))) float f32x4;

#define MFMA(a, b, c) __builtin_amdgcn_mfma_f32_16x16x32_f16((a), (b), (c), 0, 0, 0)

__device__ __forceinline__ unsigned rotl32(unsigned x, int d) {
  return (x << d) | (x >> (32 - d));
}

// JAX threefry2x32, keys (0,42), counter (0, flat), partitionable fold.
__device__ __forceinline__ float gumbel_for(unsigned flat) {
  const unsigned k0 = 0u, k1 = 42u;
  const unsigned ks2 = k0 ^ k1 ^ 0x1BD11BDAu;
  unsigned x0 = 0u + k0;
  unsigned x1 = flat + k1;
#define TF_RND(r) { x0 += x1; x1 = rotl32(x1, r); x1 ^= x0; }
  TF_RND(13) TF_RND(15) TF_RND(26) TF_RND(6)
  x0 += k1;  x1 += ks2 + 1u;
  TF_RND(17) TF_RND(29) TF_RND(16) TF_RND(24)
  x0 += ks2; x1 += k0 + 2u;
  TF_RND(13) TF_RND(15) TF_RND(26) TF_RND(6)
  x0 += k0;  x1 += k1 + 3u;
  TF_RND(17) TF_RND(29) TF_RND(16) TF_RND(24)
  x0 += k1;  x1 += ks2 + 4u;
  TF_RND(13) TF_RND(15) TF_RND(26) TF_RND(6)
  x0 += ks2; x1 += k0 + 5u;
#undef TF_RND
  unsigned bits = x0 ^ x1;
  float u = __uint_as_float((bits >> 9) | 0x3f800000u) - 1.0f;
  return -logf(-logf(u + 1e-20f) + 1e-20f);
}

// ---------------------------------------------------------------------------
// prep v3: fp32 weights -> fragment-linear f16 (scaled split) in ws.
// Thread handles 4 consecutive cc at fixed (tile, kk): float4 contiguous
// read; 4-lane groups cover 64B. Writes 2B scattered (fire-and-forget).
// 55296 threads = 216 blocks. Layout in ws identical to rounds 2-18:
// off(cc) = tile*512 + (kk>>3)*128 + cc*8 + (kk&7).
// ---------------------------------------------------------------------------
__global__ void prep_kernel(const float* __restrict__ W_enc,
                            const float* __restrict__ W_sh,
                            const float* __restrict__ W_r1,
                            _Float16* __restrict__ ws) {
  int tid = blockIdx.x * 256 + threadIdx.x;   // [0, 55296)
  if (tid < 2048) {                            // ENC: 16 tiles x 512
    int tile = tid >> 7, r4 = tid & 127;
    int kk = r4 >> 2, cc0 = (r4 & 3) * 4;
    int nt = tile >> 1, kt = tile & 1;
    int k = kt * 32 + kk, n0 = nt * 16 + cc0;
    f32x4 v4 = (f32x4)0.0f;
    if (k < 63) v4 = *(const f32x4*)(W_enc + k * 128 + n0);
    int obase = tile * 512 + (kk >> 3) * 128 + (kk & 7);
    #pragma unroll
    for (int i = 0; i < 4; ++i) {
      float v = v4[i];
      _Float16 h = (_Float16)v;
      int off = obase + (cc0 + i) * 8;
      ws[WS_ENC_H + off] = h;
      ws[WS_ENC_L + off] = (_Float16)((v - (float)h) * 2048.0f);
    }
  } else if (tid < 34816) {                    // SH: 256 tiles x 512
    int s = tid - 2048;
    int tile = s >> 7, r4 = s & 127;
    int kk = r4 >> 2, cc0 = (r4 & 3) * 4;
    int e = tile >> 5, nt = (tile >> 2) & 7, kt = tile & 3;
    int k = kt * 32 + kk, n0 = nt * 16 + cc0;
    f32x4 v4 = *(const f32x4*)(W_sh + e * 16384 + k * 128 + n0);
    int obase = tile * 512 + (kk >> 3) * 128 + (kk & 7);
    #pragma unroll
    for (int i = 0; i < 4; ++i) {
      float v = v4[i];
      _Float16 h = (_Float16)v;
      int off = obase + (cc0 + i) * 8;
      ws[WS_SH_H + off] = h;
      ws[WS_SH_L + off] = (_Float16)((v - (float)h) * 2048.0f);
    }
  } else if (tid < 55296) {                    // R1: 160 tiles x 512
    int s = tid - 34816;
    int tile = s >> 7, r4 = s & 127;
    int kk = r4 >> 2, cc0 = (r4 & 3) * 4;
    int e = tile / 20, rr = tile % 20;
    int nt = rr / 5, kt = rr % 5;
    int k = kt * 32 + kk, n0 = nt * 16 + cc0;
    f32x4 v4 = (f32x4)0.0f;
    if (k < 155) v4 = *(const f32x4*)(W_r1 + e * 9920 + k * 64 + n0);
    int obase = tile * 512 + (kk >> 3) * 128 + (kk & 7);
    #pragma unroll
    for (int i = 0; i < 4; ++i) {
      int off = obase + (cc0 + i) * 8;
      ws[WS_R1_H + off] = (_Float16)v4[i];
    }
  }
}

// ---------------------------------------------------------------------------
__global__ __launch_bounds__(NTH, 3)
void nerf_moe_kernel(const float* __restrict__ x,
                     const float* __restrict__ b_enc,
                     const float* __restrict__ b_sh,
                     const float* __restrict__ w_sig, const float* __restrict__ b_sig,
                     const float* __restrict__ b_r1,
                     const float* __restrict__ W_r2,  const float* __restrict__ b_r2,
                     const _Float16* __restrict__ wsw,
                     float* __restrict__ out) {
  __shared__ __align__(16) unsigned char smem[SMEM_SZ];
  _Float16* sYh  = (_Float16*)(smem + OFF_YH);
  float*    sH   = (float*)(smem + OFF_YH);
  _Float16* sYl  = (_Float16*)(smem + OFF_B);
  _Float16* sPEh = (_Float16*)(smem + OFF_B);
  _Float16* sPEl = (_Float16*)(smem + OFF_B + 9216);
  _Float16* sSB  = (_Float16*)(smem + OFF_B);
  float*    sRed = (float*)(smem + OFF_RED);    // [8][64] atomic

  const int t  = threadIdx.x;
  const int w  = t >> 6;        // wave id 0..3
  const int L  = t & 63;        // lane
  const int q  = L >> 4;        // quad 0..3
  const int c  = L & 15;
  const int n0 = blockIdx.x * PT;

  // zero the atomic sigma-reduction buffer (ordered vs pass 1 by barriers 1-3)
  sRed[t] = 0.0f;
  sRed[t + 256] = 0.0f;

  // ---- phase 0: xyz positional encoding ----
  for (int idx = t; idx < PT * 64; idx += NTH) {
    int p = idx >> 6, f = idx & 63;
    const float* xr = x + (size_t)(n0 + p) * 6;
    float v;
    if (f < 3)       v = xr[f];
    else if (f < 33) { int g = f - 3;  v = sinf(xr[g % 3] * (float)(1 << (g / 3))); }
    else if (f < 63) { int g = f - 33; v = cosf(xr[g % 3] * (float)(1 << (g / 3))); }
    else             v = 0.0f;
    _Float16 h = (_Float16)v;
    sPEh[p * 72 + f] = h;
    sPEl[p * 72 + f] = (_Float16)((v - (float)h) * 2048.0f);
  }
  __syncthreads();                                   // (1)

  // ---- phase A: Y = relu(PE @ W_enc + b) via MFMA, mt split in halves ----
  {
    f16x8 beh[2][2], bel[2][2];
    #pragma unroll
    for (int ntL = 0; ntL < 2; ++ntL)
      #pragma unroll
      for (int kt = 0; kt < 2; ++kt) {
        int tile = (2 * w + ntL) * 2 + kt;
        beh[ntL][kt] = *(const f16x8*)(wsw + WS_ENC_H + tile * 512 + L * 8);
        bel[ntL][kt] = *(const f16x8*)(wsw + WS_ENC_L + tile * 512 + L * 8);
      }
    f32x4 a1[4][2], a2[4][2];
    #pragma unroll
    for (int mt = 0; mt < 4; ++mt)
      #pragma unroll
      for (int ntL = 0; ntL < 2; ++ntL) { a1[mt][ntL] = (f32x4)0.0f; a2[mt][ntL] = (f32x4)0.0f; }
    // two halves over mt; pah/pal registers reused between halves
    #pragma unroll
    for (int half = 0; half < 2; ++half) {
      f16x8 pah[2][2], pal[2][2];
      #pragma unroll
      for (int m = 0; m < 2; ++m)
        #pragma unroll
        for (int kt = 0; kt < 2; ++kt) {
          int off = ((half * 2 + m) * 16 + c) * 72 + kt * 32 + q * 8;
          pah[m][kt] = *(const f16x8*)(sPEh + off);
          pal[m][kt] = *(const f16x8*)(sPEl + off);
        }
      __builtin_amdgcn_s_setprio(1);
      #pragma unroll
      for (int kt = 0; kt < 2; ++kt)
        #pragma unroll
        for (int m = 0; m < 2; ++m)
          #pragma unroll
          for (int ntL = 0; ntL < 2; ++ntL) {
            int mt = half * 2 + m;
            a1[mt][ntL] = MFMA(pah[m][kt], beh[ntL][kt], a1[mt][ntL]);
            a2[mt][ntL] = MFMA(pah[m][kt], bel[ntL][kt], a2[mt][ntL]);
            a2[mt][ntL] = MFMA(pal[m][kt], beh[ntL][kt], a2[mt][ntL]);
          }
      __builtin_amdgcn_s_setprio(0);
      asm volatile("" ::: "memory");   // fence: keep halves' LDS loads apart
    }
    __syncthreads();                                 // (2) sPE reads done -> sYl writable
    float bb0 = b_enc[(2 * w) * 16 + c];
    float bb1 = b_enc[(2 * w + 1) * 16 + c];
    #pragma unroll
    for (int mt = 0; mt < 4; ++mt)
      #pragma unroll
      for (int ntL = 0; ntL < 2; ++ntL) {
        float bb = ntL ? bb1 : bb0;
        int col = (2 * w + ntL) * 16 + c;
        #pragma unroll
        for (int r = 0; r < 4; ++r) {
          float v = fmaxf(a1[mt][ntL][r] + a2[mt][ntL][r] * INV2048 + bb, 0.0f);
          int row = mt * 16 + q * 4 + r;
          _Float16 h = (_Float16)v;
          sYh[row * 136 + col] = h;
          sYl[row * 136 + col] = (_Float16)((v - (float)h) * 2048.0f);
        }
      }
  }
  __syncthreads();                                   // (3)

  // hoist Y hi frags for kt=0..2 only (48 VGPR); kt=3 + all lo re-read per use
  f16x8 Ah[4][3];
  #pragma unroll
  for (int nt = 0; nt < 4; ++nt)
    #pragma unroll
    for (int kt = 0; kt < 3; ++kt)
      Ah[nt][kt] = *(const f16x8*)(sYh + (nt * 16 + c) * 136 + kt * 32 + q * 8);
  const f32x4 wsv0 = *(const f32x4*)(w_sig + (2 * w) * 16 + q * 4);
  const f32x4 wsv1 = *(const f32x4*)(w_sig + (2 * w + 1) * 16 + q * 4);

  // ---- pass 1: 16-step (e,i) loop, single-buffered weights ----
  float psum[4] = {0.f, 0.f, 0.f, 0.f};

  #pragma unroll 1
  for (int s = 0; s < 16; ++s) {
    int e = s >> 1, i = s & 1;
    int tbase = (e * 8 + 2 * w + i) * 4;
    f16x8 bh[4], bl[4];
    #pragma unroll
    for (int kt = 0; kt < 4; ++kt) {
      bh[kt] = *(const f16x8*)(wsw + WS_SH_H + (tbase + kt) * 512 + L * 8);
      bl[kt] = *(const f16x8*)(wsw + WS_SH_L + (tbase + kt) * 512 + L * 8);
    }
    f32x4 bb = *(const f32x4*)(b_sh + e * 128 + (2 * w + i) * 16 + q * 4);

    f32x4 a1[4], a2[4];
    #pragma unroll
    for (int nt = 0; nt < 4; ++nt) { a1[nt] = (f32x4)0.0f; a2[nt] = (f32x4)0.0f; }
    __builtin_amdgcn_s_setprio(1);
    #pragma unroll
    for (int kt = 0; kt < 4; ++kt)
      #pragma unroll
      for (int nt = 0; nt < 4; ++nt) {
        f16x8 al = *(const f16x8*)(sYl + (nt * 16 + c) * 136 + kt * 32 + q * 8);
        f16x8 ah;
        if (kt < 3) ah = Ah[nt][kt];
        else        ah = *(const f16x8*)(sYh + (nt * 16 + c) * 136 + kt * 32 + q * 8);
        a1[nt] = MFMA(bh[kt], ah, a1[nt]);
        a2[nt] = MFMA(bl[kt], ah, a2[nt]);
        a2[nt] = MFMA(bh[kt], al, a2[nt]);
      }
    __builtin_amdgcn_s_setprio(0);
    f32x4 wv = (s & 1) ? wsv1 : wsv0;
    #pragma unroll
    for (int nt = 0; nt < 4; ++nt)
      #pragma unroll
      for (int r = 0; r < 4; ++r) {
        float sv = fmaxf(fmaf(a2[nt][r], INV2048, a1[nt][r]) + bb[r], 0.0f);
        psum[nt] = fmaf(sv, wv[r], psum[nt]);
      }
    if (s & 1) {                       // end of expert e
      #pragma unroll
      for (int nt = 0; nt < 4; ++nt) {
        float v = psum[nt];
        v += __shfl_xor(v, 16);
        v += __shfl_xor(v, 32);
        if (q == 0) atomicAdd(sRed + e * 64 + nt * 16 + c, v);
        psum[nt] = 0.f;
      }
    }
  }
  __syncthreads();                                   // (4) — only pass-1 barrier

  // ---- argmax: distributed, 4 threads/point x 2 experts, gumbel inline ----
  {
    int pt = t >> 2;
    int eb = (t & 3) * 2;
    float best = -1e30f, bsig = 0.0f;
    int bide = 0;
    const float bs = b_sig[0];
    #pragma unroll
    for (int j = 0; j < 2; ++j) {
      int e = eb + j;
      float s = sRed[e * 64 + pt];
      float dotv = s + bs;
      float sig = fmaxf(dotv, 0.0f) + log1pf(expf(-fabsf(dotv)));
      float z = logf(sig + 1e-10f) / 0.166667f;
      float score = z + gumbel_for((unsigned)((n0 + pt) * 8 + e));
      if (score > best) { best = score; bsig = sig; bide = e; }
    }
    #pragma unroll
    for (int m = 1; m <= 2; m <<= 1) {
      float oS  = __shfl_xor(best, m);
      float oSg = __shfl_xor(bsig, m);
      int   oI  = __shfl_xor(bide, m);
      if (oS > best || (oS == best && oI < bide)) { best = oS; bsig = oSg; bide = oI; }
    }
    if ((t & 3) == 0) {
      S_BID(pt) = bide;                // row-pad slot; sYl dead, sSB not yet
      out[(size_t)(n0 + pt) * 4 + 3] = bsig;
    }
  }
  __syncthreads();                                   // (5)

  // ---- bucket lists: wave-0 ballot build ----
  if (t < 64) {
    int bid = S_BID(t);
    unsigned long long below = t ? ((~0ULL) >> (64 - t)) : 0ULL;
    int off = 0;
    #pragma unroll
    for (int e = 0; e < 8; ++e) {
      unsigned long long m = __ballot(bid == e);
      int cnt = __popcll(m);
      if (t == e) { S_CNT(e) = cnt; S_OFF(e) = off; }
      if (bid == e) {
        int rank = __popcll(m & below);
        S_LIST(off + rank) = t;
      }
      off += cnt;
    }
  }
  __syncthreads();                                   // (6)

  // ---- pass 2a: viewdir PE into sSB + winner S recompute (transposed) ----
  for (int idx = t; idx < PT * 32; idx += NTH) {
    int s = idx >> 5, cc = idx & 31;
    int pt = S_LIST(s);
    const float* xr = x + (size_t)(n0 + pt) * 6 + 3;
    float v;
    if (cc < 3)       v = xr[cc];
    else if (cc < 15) { int g = cc - 3;  v = sinf(xr[g % 3] * (float)(1 << (g / 3))); }
    else if (cc < 27) { int g = cc - 15; v = cosf(xr[g % 3] * (float)(1 << (g / 3))); }
    else              v = 0.0f;
    sSB[s * 168 + 128 + cc] = (_Float16)v;
  }
  #pragma unroll 1
  for (int ei = 0; ei < 2; ++ei) {
    int e = 2 * w + ei;
    int cnt = S_CNT(e), off = S_OFF(e);
    for (int base = 0; base < cnt; base += 16) {
      int sidx = base + c; if (sidx >= cnt) sidx = cnt - 1;
      int pt = S_LIST(off + sidx);
      f16x8 yb[4];
      #pragma unroll
      for (int kt = 0; kt < 4; ++kt)
        yb[kt] = *(const f16x8*)(sYh + pt * 136 + kt * 32 + q * 8);
      f32x4 acc[8];
      #pragma unroll
      for (int jt = 0; jt < 8; ++jt) acc[jt] = (f32x4)0.0f;
      // jt split into 2 halves of 4: <=16 weight frags in flight (64 VGPR)
      #pragma unroll
      for (int jh = 0; jh < 2; ++jh) {
        __builtin_amdgcn_s_setprio(1);
        #pragma unroll
        for (int jt2 = 0; jt2 < 4; ++jt2) {
          int jt = jh * 4 + jt2;
          #pragma unroll
          for (int kt = 0; kt < 4; ++kt) {
            f16x8 a = *(const f16x8*)(wsw + WS_SH_H + ((e * 8 + jt) * 4 + kt) * 512 + L * 8);
            acc[jt] = MFMA(a, yb[kt], acc[jt]);
          }
        }
        __builtin_amdgcn_s_setprio(0);
        asm volatile("" ::: "memory"); // fence: limit weight-load hoisting
      }
      bool wr = (base + c) < cnt;
      int slot = off + base + c;
      #pragma unroll
      for (int jt = 0; jt < 8; ++jt) {
        f32x4 bb = *(const f32x4*)(b_sh + e * 128 + jt * 16 + q * 4);
        f16x4 v;
        #pragma unroll
        for (int r = 0; r < 4; ++r)
          v[r] = (_Float16)fmaxf(acc[jt][r] + bb[r], 0.0f);
        if (wr) *(f16x4*)(sSB + slot * 168 + jt * 16 + q * 4) = v;
      }
    }
  }
  __syncthreads();                                   // (7) sYh dead -> sH writable

  // ---- pass 2b: rgb layer 1 via MFMA ([S;vd] @ W_r1) ----
  #pragma unroll 1
  for (int ei = 0; ei < 2; ++ei) {
    int e = 2 * w + ei;
    int cnt = S_CNT(e), off = S_OFF(e);
    for (int base = 0; base < cnt; base += 16) {
      int sidx = base + c; if (sidx >= cnt) sidx = cnt - 1;
      int slot = off + sidx;
      f16x8 ag[5];
      #pragma unroll
      for (int kt = 0; kt < 5; ++kt)
        ag[kt] = *(const f16x8*)(sSB + slot * 168 + kt * 32 + q * 8);
      f32x4 hacc[4];
      #pragma unroll
      for (int nt = 0; nt < 4; ++nt) hacc[nt] = (f32x4)0.0f;
      // nt split into 2 halves of 2: <=10 weight frags in flight (40 VGPR)
      #pragma unroll
      for (int nh = 0; nh < 2; ++nh) {
        __builtin_amdgcn_s_setprio(1);
        #pragma unroll
        for (int nt2 = 0; nt2 < 2; ++nt2) {
          int nt = nh * 2 + nt2;
          #pragma unroll
          for (int kt = 0; kt < 5; ++kt) {
            f16x8 bf = *(const f16x8*)(wsw + WS_R1_H + ((e * 4 + nt) * 5 + kt) * 512 + L * 8);
            hacc[nt] = MFMA(ag[kt], bf, hacc[nt]);
          }
        }
        __builtin_amdgcn_s_setprio(0);
        asm volatile("" ::: "memory"); // fence: limit weight-load hoisting
      }
      #pragma unroll
      for (int nt = 0; nt < 4; ++nt) {
        float bb = b_r1[e * 64 + nt * 16 + c];
        #pragma unroll
        for (int r = 0; r < 4; ++r) {
          int m = q * 4 + r;
          if (base + m < cnt)
            sH[(off + base + m) * 68 + nt * 16 + c] = fmaxf(hacc[nt][r] + bb, 0.0f);
        }
      }
    }
  }
  __syncthreads();                                   // (8)

  // ---- layer 2: rgb = sigmoid(h @ W_r2 + b) ----
  if (t < 192) {
    int s = t / 3, o = t - s * 3;
    int pt = S_LIST(s);
    int e = S_BID(pt);
    float a = b_r2[e * 3 + o];
    const float* w2 = W_r2 + e * 192 + o;
    #pragma unroll
    for (int jj = 0; jj < 64; jj += 4) {
      f32x4 h4 = *(const f32x4*)(sH + s * 68 + jj);
      a = fmaf(h4.x, w2[jj * 3], a);
      a = fmaf(h4.y, w2[jj * 3 + 3], a);
      a = fmaf(h4.z, w2[jj * 3 + 6], a);
      a = fmaf(h4.w, w2[jj * 3 + 9], a);
    }
    out[(size_t)(n0 + pt) * 4 + o] = 1.0f / (1.0f + expf(-a));
  }
}

extern "C" void kernel_launch(void* const* d_in, const int* in_sizes, int n_in,
                              void* d_out, int out_size, void* d_ws, size_t ws_size,
                              hipStream_t stream) {
  (void)in_sizes; (void)n_in; (void)ws_size; (void)out_size;
  const float* x     = (const float*)d_in[0];
  const float* W_enc = (const float*)d_in[1];
  const float* b_enc = (const float*)d_in[2];
  const float* W_sh  = (const float*)d_in[3];
  const float* b_sh  = (const float*)d_in[4];
  const float* w_sig = (const float*)d_in[5];
  const float* b_sig = (const float*)d_in[6];
  const float* W_r1  = (const float*)d_in[7];
  const float* b_r1  = (const float*)d_in[8];
  const float* W_r2  = (const float*)d_in[9];
  const float* b_r2  = (const float*)d_in[10];
  _Float16* ws = (_Float16*)d_ws;     // needs 720896 B
  float* outp = (float*)d_out;
  prep_kernel<<<216, 256, 0, stream>>>(W_enc, W_sh, W_r1, ws);
  nerf_moe_kernel<<<NBLK, NTH, 0, stream>>>(x, b_enc, b_sh, w_sig, b_sig,
                                            b_r1, W_r2, b_r2, ws, outp);
}